// Round 10
// baseline (162.452 us; speedup 1.0000x reference)
//
#include <hip/hip_runtime.h>

// MechanisticNRTLLoss — B=1e6 samples, scalar fp32 loss.
// R19 = R18 (GD-free, best: ~31us kernel) + register-neutral packed math.
//  - VGPR cliff (m69): waves/SIMD halve at 64 regs. R9/R18 sit at 48 — every
//    register-hungry packing (R11/R16/R17) crossed 64 and lost residency.
//  - This round packs over the COMPONENT index inside ln_gamma3: the i=0,1
//    lanes of the d/A dot products and j=0,1 of the term-2 sum use v_pk_*
//    with row-adjacent matrix pairs {M[r][0],M[r][1]} — stored once, NOT
//    broadcast: zero extra registers, ~25% fewer ops in the hot function.
//  - sup and M construction also packed (operands already adjacent).
//  - Identical fma contraction order per half -> numerics match R18.

constexpr float ALPHA    = 0.3f;
constexpr float R_GAS    = 8.314462618f;
constexpr float EPS      = 1e-12f;
constexpr float TAU_CLIP = 10.0f;
constexpr float LN_CLIP  = 20.0f;

constexpr float LOG2E = 1.44269504088896340736f;
constexpr float LN2   = 0.69314718055994530942f;

typedef float v2f __attribute__((ext_vector_type(2)));

__device__ __forceinline__ v2f make2(float s) { return (v2f){s, s}; }
__device__ __forceinline__ float clipf(float v, float lo, float hi) {
    return fminf(fmaxf(v, lo), hi);
}
__device__ __forceinline__ float fast_rcp(float x) { return __builtin_amdgcn_rcpf(x); }
__device__ __forceinline__ v2f pk_rcp(v2f a) {
    return (v2f){__builtin_amdgcn_rcpf(a.x), __builtin_amdgcn_rcpf(a.y)};
}
__device__ __forceinline__ v2f pk_max(v2f a, v2f b) { return __builtin_elementwise_max(a, b); }
__device__ __forceinline__ v2f pk_min(v2f a, v2f b) { return __builtin_elementwise_min(a, b); }
__device__ __forceinline__ v2f pk_clip(v2f v, float lo, float hi) {
    return pk_min(pk_max(v, make2(lo)), make2(hi));
}
__device__ __forceinline__ v2f nt_load2(const float* p) {
    return __builtin_nontemporal_load((const v2f*)p);
}
__device__ __forceinline__ float nt_load(const float* p) {
    return __builtin_nontemporal_load(p);
}

// NRTL matrices, component-packed: row r holds pair {m[r][0],m[r][1]} + col-2
// scalar. Same 18 live values as the scalar form — zero extra registers.
struct MatsC {
    v2f  G01[3];  float G2[3];
    v2f tG01[3];  float tG2[3];
};

// Component-packed ln_gamma (one composition):
//   d_i = sum_j x_j G[j][i]; lanes i=0,1 packed, i=2 scalar.
//   term2: s_i = ratio_i + sum_j c_j (tG[i][j] - G[i][j] ratio_j);
//   j=0,1 packed (row pairs), j=2 scalar.
__device__ __forceinline__ void ln_gamma3c(const float x[3], const MatsC& M, float lg[3]) {
    const v2f vx0 = make2(x[0]), vx1 = make2(x[1]), vx2 = make2(x[2]);
    v2f d01 = vx0 * M.G01[0]  + vx1 * M.G01[1]  + vx2 * M.G01[2];
    v2f A01 = vx0 * M.tG01[0] + vx1 * M.tG01[1] + vx2 * M.tG01[2];
    d01 = pk_max(d01, make2(EPS));
    v2f inv01   = pk_rcp(d01);
    v2f ratio01 = A01 * inv01;
    v2f c01     = (v2f){x[0], x[1]} * inv01;

    float d2 = x[0] * M.G2[0] + x[1] * M.G2[1] + x[2] * M.G2[2];
    d2 = fmaxf(d2, EPS);
    float A2     = x[0] * M.tG2[0] + x[1] * M.tG2[1] + x[2] * M.tG2[2];
    float inv2   = fast_rcp(d2);
    float ratio2 = A2 * inv2;
    float c2     = x[2] * inv2;

    const float ratio_s[3] = {ratio01.x, ratio01.y, ratio2};
#pragma unroll
    for (int i = 0; i < 3; ++i) {
        v2f t01 = c01 * (M.tG01[i] - M.G01[i] * ratio01);
        float s = ratio_s[i] + t01.x + t01.y
                + c2 * (M.tG2[i] - M.G2[i] * ratio2);
        lg[i] = clipf(s, -LN_CLIP, LN_CLIP);
    }
}

__device__ __forceinline__ void renorm3(float x[3]) {
    x[0] = fmaxf(x[0], 0.0f);
    x[1] = fmaxf(x[1], 0.0f);
    x[2] = fmaxf(x[2], 0.0f);
    float inv = fast_rcp(fmaxf(x[0] + x[1] + x[2], EPS));
    x[0] *= inv; x[1] *= inv; x[2] *= inv;
}

__global__ __launch_bounds__(256, 3) void nrtl_loss_kernel(
    const float* __restrict__ pred,   // (B,6)
    const float* __restrict__ target, // (B,6)
    const float* __restrict__ Tarr,   // (B,)
    const float* __restrict__ g,      // (B,3,3)
    const float* __restrict__ dirs,   // (2,B,3) — unread: GD term identically 0
    const float* __restrict__ noise,  // (4,B,3)
    float* __restrict__ partials, int B)
{
    const int i = blockIdx.x * blockDim.x + threadIdx.x;
    float contrib = 0.0f;

    if (i < B) {
        const float* prow = pred   + (size_t)i * 6;
        const float* trow = target + (size_t)i * 6;
        const float* grow = g      + (size_t)i * 9;

        // ============== stage inputs, in first-use order ==============
        v2f p01 = nt_load2(prow);
        v2f p23 = nt_load2(prow + 2);
        v2f p45 = nt_load2(prow + 4);
        v2f t01 = nt_load2(trow);
        v2f t23 = nt_load2(trow + 2);
        v2f t45 = nt_load2(trow + 4);
        float Tv = nt_load(Tarr + i);
        float gv[9];
#pragma unroll
        for (int k = 0; k < 9; ++k) gv[k] = nt_load(grow + k);
        float nv[4][3];
#pragma unroll
        for (int tr = 0; tr < 4; ++tr) {
            const float* nrow = noise + ((size_t)tr * B + i) * 3;
#pragma unroll
            for (int k = 0; k < 3; ++k) nv[tr][k] = nt_load(nrow + k);
        }
        __builtin_amdgcn_sched_barrier(0);

        // ---------------- supervised MSE (packed) ----------------
        float sup;
        {
            v2f s01 = p01 - t01, s23 = p23 - t23, s45 = p45 - t45;
            v2f acc = s01 * s01 + s23 * s23 + s45 * s45;
            sup = acc.x + acc.y;
        }

        float xE[3] = {p01.x, p01.y, p23.x};
        float xR[3] = {p23.y, p45.x, p45.y};
        renorm3(xE);
        renorm3(xR);

        // ---------------- NRTL matrices (row-pair packed) ----------------
        const float Tc = fmaxf(Tv, 1.0f);
        const float invRT = fast_rcp(R_GAS * Tc);
        MatsC M;
#pragma unroll
        for (int a = 0; a < 3; ++a) {
            v2f ta01 = pk_clip((v2f){gv[a * 3], gv[a * 3 + 1]} * make2(invRT),
                               -TAU_CLIP, TAU_CLIP);
            v2f e01  = make2(-ALPHA * LOG2E) * ta01;
            v2f G01  = (v2f){__builtin_amdgcn_exp2f(e01.x),
                             __builtin_amdgcn_exp2f(e01.y)};
            M.G01[a]  = G01;
            M.tG01[a] = ta01 * G01;
            float ta2 = clipf(gv[a * 3 + 2] * invRT, -TAU_CLIP, TAU_CLIP);
            float G2  = __builtin_amdgcn_exp2f((-ALPHA * LOG2E) * ta2);
            M.G2[a]  = G2;
            M.tG2[a] = ta2 * G2;
        }

        float lgE[3], lgR[3];
        ln_gamma3c(xE, M, lgE);
        ln_gamma3c(xR, M, lgR);

        float logxE[3];
        float phy = 0.0f;
#pragma unroll
        for (int k = 0; k < 3; ++k) {
            logxE[k] = LN2 * __builtin_amdgcn_logf(fmaxf(xE[k], EPS));
            float logxR = LN2 * __builtin_amdgcn_logf(fmaxf(xR[k], EPS));
            float r = logxE[k] + lgE[k] - logxR - lgR[k];
            phy += r * r;
        }

        // TPD: hoist the per-sample base ln(xE)+lgE out of the trial loop.
        float base[3];
#pragma unroll
        for (int k = 0; k < 3; ++k) base[k] = logxE[k] + lgE[k];

        float tpdsum = 0.0f;
#pragma unroll
        for (int tr = 0; tr < 4; ++tr) {
            float w[3];
#pragma unroll
            for (int k = 0; k < 3; ++k) w[k] = xE[k] + nv[tr][k];
            renorm3(w);
            float lgw[3];
            ln_gamma3c(w, M, lgw);
            float tpd = 0.0f;
#pragma unroll
            for (int k = 0; k < 3; ++k) {
                float logw = LN2 * __builtin_amdgcn_logf(fmaxf(w[k], EPS));
                tpd += w[k] * (logw + lgw[k] - base[k]);
            }
            tpdsum += fmaxf(-tpd, 0.0f);  // MARGIN = 0
        }

        const float invB = 1.0f / (float)B;
        contrib = invB * (sup * (1.0f / 6.0f)
                          + phy * (1.0f / 3.0f)
                          + 0.025f * tpdsum);
    }

    // ---- block reduction: wave shuffle then LDS across 4 waves ----
#pragma unroll
    for (int off = 32; off > 0; off >>= 1)
        contrib += __shfl_down(contrib, off, 64);

    __shared__ float ssum[4];
    const int lane = threadIdx.x & 63;
    const int wid  = threadIdx.x >> 6;
    if (lane == 0) ssum[wid] = contrib;
    __syncthreads();
    if (threadIdx.x == 0) {
        partials[blockIdx.x] = ssum[0] + ssum[1] + ssum[2] + ssum[3];
    }
}

__global__ __launch_bounds__(256) void reduce_kernel(
    const float* __restrict__ partials, int n, float* __restrict__ out)
{
    double sacc = 0.0;
    for (int j = threadIdx.x; j < n; j += 256) sacc += (double)partials[j];
#pragma unroll
    for (int off = 32; off > 0; off >>= 1)
        sacc += __shfl_down(sacc, off, 64);
    __shared__ double ds[4];
    const int lane = threadIdx.x & 63;
    const int wid  = threadIdx.x >> 6;
    if (lane == 0) ds[wid] = sacc;
    __syncthreads();
    if (threadIdx.x == 0) out[0] = (float)(ds[0] + ds[1] + ds[2] + ds[3]);
}

extern "C" void kernel_launch(void* const* d_in, const int* in_sizes, int n_in,
                              void* d_out, int out_size, void* d_ws, size_t ws_size,
                              hipStream_t stream) {
    const float* pred   = (const float*)d_in[0];
    const float* target = (const float*)d_in[1];
    const float* Tarr   = (const float*)d_in[2];
    const float* g      = (const float*)d_in[3];
    const float* dirs   = (const float*)d_in[4];
    const float* noise  = (const float*)d_in[5];
    const int B = in_sizes[2];  // T is (B,)

    float* partials = (float*)d_ws;
    float* out      = (float*)d_out;

    const int block = 256;
    const int grid  = (B + block - 1) / block;
    nrtl_loss_kernel<<<grid, block, 0, stream>>>(pred, target, Tarr, g, dirs, noise, partials, B);
    reduce_kernel<<<1, block, 0, stream>>>(partials, grid, out);
}